// Round 3
// baseline (160.346 us; speedup 1.0000x reference)
//
#include <hip/hip_runtime.h>
#include <hip/hip_bf16.h>

typedef __bf16    bf16x8  __attribute__((ext_vector_type(8)));
typedef __bf16    bf16x4  __attribute__((ext_vector_type(4)));
typedef _Float16  half8   __attribute__((ext_vector_type(8)));
typedef _Float16  half4   __attribute__((ext_vector_type(4)));
typedef float     floatx4 __attribute__((ext_vector_type(4)));

constexpr int Bc  = 2;
constexpr int Hc  = 16;
constexpr int Lc  = 2048;
constexpr int Dc  = 64;
constexpr int BHn = Bc * Hc;     // 32
constexpr int BM  = 128;         // query rows per block (2 strips of 16 per wave)
constexpr int BN  = 64;          // keys per tile
constexpr int NQT = Lc / BM;     // 16 query tiles
constexpr int LDP = 72;          // padded LDS row stride (elems): 144 B rows, 16B-aligned

// ---- pre-pass 1: K fp32 -> bf16, same [bh][key][d] layout ----
__global__ void cvt_k(const float* __restrict__ kp, __bf16* __restrict__ k16) {
    size_t i = ((size_t)blockIdx.x * 256 + threadIdx.x) * 4;
    floatx4 v = *(const floatx4*)(kp + i);
    bf16x4 b;
    b[0] = (__bf16)v[0]; b[1] = (__bf16)v[1]; b[2] = (__bf16)v[2]; b[3] = (__bf16)v[3];
    *(bf16x4*)(k16 + i) = b;
}

// ---- pre-pass 2: V fp32 [bh][key][d] -> fp16 transposed [bh][d][key] ----
__global__ void transpose_v(const float* __restrict__ vp, _Float16* __restrict__ vt) {
    const int bh  = (int)(blockIdx.x >> 5);
    const int kt  = (int)(blockIdx.x & 31);
    const int key = kt * 64 + (int)(threadIdx.x & 63);
    const int d0  = ((int)threadIdx.x >> 6) * 16;
    const float* src = vp + ((size_t)bh * Lc + key) * Dc;   // one 64B cacheline per lane per d-block
    _Float16*    dst = vt + (size_t)bh * Dc * Lc + key;
    #pragma unroll
    for (int i = 0; i < 16; ++i) {
        const int d = d0 + i;
        dst[(size_t)d * Lc] = (_Float16)src[d];             // writes: 64 lanes contiguous, coalesced
    }
}

// ---- main kernel ----
__global__ __launch_bounds__(256, 2)
void taylor_attn(const float* __restrict__ qp, const __bf16* __restrict__ k16,
                 const _Float16* __restrict__ v16, float* __restrict__ op)
{
    alignas(16) __shared__ unsigned char smem[BM * LDP * 2];
    __bf16*   Qs = (__bf16*)smem;                       // 128 x 72 bf16 (Q staging, then reused)
    __bf16*   Ks = (__bf16*)smem;                       // 64 x 72 bf16
    _Float16* VT = (_Float16*)(smem + 64 * LDP * 2);    // 64 x 72 fp16 (V^T: [d][key])

    const int tid  = threadIdx.x;
    const int wv   = tid >> 6;
    const int lane = tid & 63;
    const int lm   = lane & 15;
    const int quad = lane >> 4;

    const int qi = (NQT - 1) - (int)(blockIdx.x >> 5);   // heavy tiles dispatched first
    const int bh = (int)(blockIdx.x & (BHn - 1));
    const int q0 = qi * BM;
    const int jmax = 2 * qi + 1;

    const float*    qbase = qp  + ((size_t)bh * Lc + q0) * Dc;
    const __bf16*   kbase = k16 + (size_t)bh * Lc * Dc;
    const _Float16* vbase = v16 + (size_t)bh * Dc * Lc;

    // ---- stage Q (fp32 -> bf16), extract per-strip B-frags, release LDS ----
    {
        const int r0 = tid >> 4, c4 = tid & 15;
        #pragma unroll
        for (int rep = 0; rep < 8; ++rep) {
            const int row = r0 + rep * 16;
            floatx4 v = *(const floatx4*)(qbase + row * Dc + c4 * 4);
            bf16x4 b;
            b[0] = (__bf16)v[0]; b[1] = (__bf16)v[1]; b[2] = (__bf16)v[2]; b[3] = (__bf16)v[3];
            *(bf16x4*)&Qs[row * LDP + c4 * 4] = b;
        }
    }
    __syncthreads();
    bf16x8 qa[2][2];   // [strip][kf]; B-operand frag: n=lm (qrow), k=kf*32+quad*8+j
    #pragma unroll
    for (int st = 0; st < 2; ++st)
        #pragma unroll
        for (int kf = 0; kf < 2; ++kf)
            qa[st][kf] = *(const bf16x8*)&Qs[(32 * wv + 16 * st + lm) * LDP + kf * 32 + quad * 8];
    __syncthreads();

    floatx4 oacc[2][4] = {};        // O^T accum: [strip][d-block]; col=qrow=lm, row=d=quad*4+r
    float   zacc[2] = {0.f, 0.f};

    for (int j = 0; j <= jmax; ++j) {
        // ---- stage K tile (bf16) and V^T tile (fp16), pure b128 copies ----
        {
            const __bf16*   kt  = kbase + (size_t)j * BN * Dc;
            const _Float16* vtt = vbase + (size_t)j * BN;
            #pragma unroll
            for (int rep = 0; rep < 2; ++rep) {
                const int c = tid + 256 * rep, row = c >> 3, col = c & 7;
                *(bf16x8*)&Ks[row * LDP + col * 8] = *(const bf16x8*)(kt + row * Dc + col * 8);
            }
            #pragma unroll
            for (int rep = 0; rep < 2; ++rep) {
                const int c = tid + 256 * rep, row = c >> 3, col = c & 7;   // row = d
                *(half8*)&VT[row * LDP + col * 8] = *(const half8*)(vtt + (size_t)row * Lc + col * 8);
            }
        }
        __syncthreads();

        // ---- S^T = K * Q^T : D[key][qrow], shared K-frags serve both strips ----
        floatx4 sacc[2][4] = {};
        #pragma unroll
        for (int kb = 0; kb < 4; ++kb)
            #pragma unroll
            for (int kf = 0; kf < 2; ++kf) {
                bf16x8 ka = *(const bf16x8*)&Ks[(16 * kb + lm) * LDP + kf * 32 + quad * 8];
                sacc[0][kb] = __builtin_amdgcn_mfma_f32_16x16x32_bf16(ka, qa[0][kf], sacc[0][kb], 0, 0, 0);
                sacc[1][kb] = __builtin_amdgcn_mfma_f32_16x16x32_bf16(ka, qa[1][kf], sacc[1][kb], 0, 0, 0);
            }

        // ---- Taylor + causal mask + z, all in registers; pack W as fp16 B-frags ----
        half4 wb[2][4];
        bool  live[2];
        #pragma unroll
        for (int st = 0; st < 2; ++st) {
            const int strip_lo = q0 + 32 * wv + 16 * st;
            live[st] = (j * BN <= strip_lo + 15);          // any unmasked key for this strip?
            if (!live[st]) continue;
            const bool nm = (j * BN + 63 > strip_lo);      // diagonal-crossing tile
            const int qrow = strip_lo + lm;
            #pragma unroll
            for (int kb = 0; kb < 4; ++kb) {
                half4 h;
                #pragma unroll
                for (int r = 0; r < 4; ++r) {
                    const float s = sacc[st][kb][r] * 0.125f;   // scale = D^-0.5
                    float w = 1.0f + s + 0.5f * s * s;
                    if (nm) {
                        const int key = j * BN + 16 * kb + 4 * quad + r;
                        w = (key <= qrow) ? w : 0.0f;
                    }
                    zacc[st] += w;
                    h[r] = (_Float16)w;
                }
                wb[st][kb] = h;
            }
        }

        // ---- O^T += V^T * W^T : A = V^T frags (b64 from LDS), B = wb (in regs) ----
        #pragma unroll
        for (int db = 0; db < 4; ++db)
            #pragma unroll
            for (int kb = 0; kb < 4; ++kb) {
                half4 va = *(const half4*)&VT[(16 * db + lm) * LDP + 16 * kb + 4 * quad];
                if (live[0]) oacc[0][db] = __builtin_amdgcn_mfma_f32_16x16x16f16(va, wb[0][kb], oacc[0][db], 0, 0, 0);
                if (live[1]) oacc[1][db] = __builtin_amdgcn_mfma_f32_16x16x16f16(va, wb[1][kb], oacc[1][db], 0, 0, 0);
            }
        __syncthreads();
    }

    // ---- finalize: z reduce across quads (lanes ^16, ^32), normalize, store ----
    #pragma unroll
    for (int st = 0; st < 2; ++st) {
        float z = zacc[st];
        z += __shfl_xor(z, 16);
        z += __shfl_xor(z, 32);
        const float inv = 1.0f / (z + 1e-6f);
        const int qrow = q0 + 32 * wv + 16 * st + lm;
        float* orow = op + ((size_t)bh * Lc + qrow) * Dc;
        #pragma unroll
        for (int db = 0; db < 4; ++db)
            #pragma unroll
            for (int r = 0; r < 4; ++r)
                orow[16 * db + 4 * quad + r] = oacc[st][db][r] * inv;
    }
}

extern "C" void kernel_launch(void* const* d_in, const int* in_sizes, int n_in,
                              void* d_out, int out_size, void* d_ws, size_t ws_size,
                              hipStream_t stream) {
    const float* q = (const float*)d_in[0];
    const float* k = (const float*)d_in[1];
    const float* v = (const float*)d_in[2];
    float* o = (float*)d_out;

    __bf16*   k16 = (__bf16*)d_ws;                                    // 8 MB
    _Float16* v16 = (_Float16*)((char*)d_ws + (size_t)BHn * Lc * Dc * 2);  // 8 MB

    const int nelem_blocks = (BHn * Lc * Dc) / (4 * 256);   // 4096
    cvt_k<<<dim3(nelem_blocks), dim3(256), 0, stream>>>(k, k16);
    transpose_v<<<dim3(BHn * (Lc / 64)), dim3(256), 0, stream>>>(v, v16);
    taylor_attn<<<dim3(NQT * BHn), dim3(256), 0, stream>>>(q, k16, v16, o);
}

// Round 4
// 144.901 us; speedup vs baseline: 1.1066x; 1.1066x over previous
//
#include <hip/hip_runtime.h>
#include <hip/hip_bf16.h>

typedef __bf16    bf16x8  __attribute__((ext_vector_type(8)));
typedef __bf16    bf16x4  __attribute__((ext_vector_type(4)));
typedef _Float16  half8   __attribute__((ext_vector_type(8)));
typedef _Float16  half4   __attribute__((ext_vector_type(4)));
typedef float     floatx4 __attribute__((ext_vector_type(4)));

constexpr int Bc  = 2;
constexpr int Hc  = 16;
constexpr int Lc  = 2048;
constexpr int Dc  = 64;
constexpr int BHn = Bc * Hc;     // 32
constexpr int BM  = 128;         // query rows per block (2 strips of 16 per wave)
constexpr int BN  = 64;          // keys per tile
constexpr int NQT = Lc / BM;     // 16 query tiles
constexpr int LDP = 72;          // padded LDS row stride: 144 B rows, 16B-aligned, <=2-way conflicts
constexpr int BUFB = BN * LDP * 2 + Dc * LDP * 2;   // 18432 B per double-buffer slot

// ---- fused pre-pass: K fp32->bf16 (blocks 0..1023), V fp32 -> fp16 transposed+key-permuted ----
// V^T layout: [bh][d][pcol] where within each 32-key group, key (kb',q,r)=(k5>>4,(k5>>2)&3,k5&3)
// goes to logical column 8q+4kb'+r — so PV A-frags (k=quad*8+j) read b128-contiguous, and the
// register W B-frags (keys 16kb+4quad+r) pack as half8 [kb0 r0..3 | kb1 r0..3].
__global__ void prep(const float* __restrict__ kp, const float* __restrict__ vp,
                     __bf16* __restrict__ k16, _Float16* __restrict__ v16) {
    const int bid = blockIdx.x, tid = threadIdx.x;
    if (bid < 1024) {
        const size_t base = (size_t)bid * 4096 + tid * 4;
        #pragma unroll
        for (int rep = 0; rep < 4; ++rep) {
            const size_t i = base + rep * 1024;
            floatx4 v = *(const floatx4*)(kp + i);
            bf16x4 b;
            b[0] = (__bf16)v[0]; b[1] = (__bf16)v[1]; b[2] = (__bf16)v[2]; b[3] = (__bf16)v[3];
            *(bf16x4*)(k16 + i) = b;
        }
    } else {
        const int vb  = bid - 1024;
        const int bh  = vb >> 5, kt = vb & 31;
        const int key = kt * 64 + (tid & 63);
        const int k5  = key & 31;
        const int pcol = (key & ~31) | (((k5 >> 2) & 3) * 8 + ((k5 >> 4) & 1) * 4 + (k5 & 3));
        const int d0  = (tid >> 6) * 16;
        const float* src = vp + ((size_t)bh * Lc + key) * Dc;
        _Float16*    dst = v16 + (size_t)bh * Dc * Lc + pcol;
        #pragma unroll
        for (int i = 0; i < 16; ++i) {
            const int d = d0 + i;
            dst[(size_t)d * Lc] = (_Float16)src[d];
        }
    }
}

// ---- main kernel ----
__global__ __launch_bounds__(256, 2)
void taylor_attn(const float* __restrict__ qp, const __bf16* __restrict__ k16,
                 const _Float16* __restrict__ v16, float* __restrict__ op)
{
    alignas(16) __shared__ unsigned char smem[2 * BUFB];   // 36864 B: double-buffered {Ks, VT}

    const int tid  = threadIdx.x;
    const int wv   = tid >> 6;
    const int lane = tid & 63;
    const int lm   = lane & 15;
    const int quad = lane >> 4;

    // complement pairing: blocks b and b+256 land on the same CU (round-robin dispatch);
    // give them q-tiles (15-qslot) and (qslot) so per-CU KV-tile count is constant (34).
    const int cu    = (int)(blockIdx.x & 255);
    const int snd   = (int)(blockIdx.x >> 8);
    const int bh    = cu & 31;
    const int qslot = cu >> 5;
    const int qi    = snd ? qslot : (NQT - 1 - qslot);
    const int q0    = qi * BM;
    const int jmax  = 2 * qi + 1;

    const float*    qbase = qp  + ((size_t)bh * Lc + q0) * Dc;
    const __bf16*   kbase = k16 + (size_t)bh * Lc * Dc;
    const _Float16* vbase = v16 + (size_t)bh * Dc * Lc;

    const int gr = tid >> 3;          // granule row 0..31
    const int gc = (tid & 7) * 8;     // granule col (elements)

    // ---- prefetch tile 0 into registers (in flight during Q staging) ----
    bf16x8 kr[2]; half8 vr[2];
    kr[0] = *(const bf16x8*)(kbase + 8 * tid);
    kr[1] = *(const bf16x8*)(kbase + 8 * (tid + 256));
    vr[0] = *(const half8*)(vbase + (size_t)gr * Lc + gc);
    vr[1] = *(const half8*)(vbase + (size_t)(gr + 32) * Lc + gc);

    // ---- stage Q (fp32 -> bf16) into smem, extract per-strip B-frags, release ----
    {
        __bf16* Qs = (__bf16*)smem;
        const int r0 = tid >> 4, c4 = tid & 15;
        #pragma unroll
        for (int rep = 0; rep < 8; ++rep) {
            const int row = r0 + rep * 16;
            floatx4 v = *(const floatx4*)(qbase + row * Dc + c4 * 4);
            bf16x4 b;
            b[0] = (__bf16)v[0]; b[1] = (__bf16)v[1]; b[2] = (__bf16)v[2]; b[3] = (__bf16)v[3];
            *(bf16x4*)&Qs[row * LDP + c4 * 4] = b;
        }
    }
    __syncthreads();
    bf16x8 qa[2][2];   // [strip][kf]; B-frag: n=lm (qrow), k=kf*32+quad*8+j
    {
        __bf16* Qs = (__bf16*)smem;
        #pragma unroll
        for (int st = 0; st < 2; ++st)
            #pragma unroll
            for (int kf = 0; kf < 2; ++kf)
                qa[st][kf] = *(const bf16x8*)&Qs[(32 * wv + 16 * st + lm) * LDP + kf * 32 + quad * 8];
    }
    __syncthreads();

    floatx4 oacc[2][4] = {};        // O^T accum: [strip][d-block]; col=qrow=lm, row=d=quad*4+r
    float   zacc[2] = {0.f, 0.f};

    for (int j = 0; j <= jmax; ++j) {
        __bf16*   Ks = (__bf16*)(smem + (j & 1) * BUFB);
        _Float16* VT = (_Float16*)(smem + (j & 1) * BUFB + BN * LDP * 2);

        // ---- write the prefetched tile into this iteration's buffer ----
        *(bf16x8*)&Ks[gr * LDP + gc]        = kr[0];
        *(bf16x8*)&Ks[(gr + 32) * LDP + gc] = kr[1];
        *(half8*)&VT[gr * LDP + gc]         = vr[0];
        *(half8*)&VT[(gr + 32) * LDP + gc]  = vr[1];

        // ---- issue next tile's global loads (hidden under this iteration's compute) ----
        if (j < jmax) {
            const __bf16*   ktn = kbase + (size_t)(j + 1) * BN * Dc;
            const _Float16* vtn = vbase + (size_t)(j + 1) * BN;
            kr[0] = *(const bf16x8*)(ktn + 8 * tid);
            kr[1] = *(const bf16x8*)(ktn + 8 * (tid + 256));
            vr[0] = *(const half8*)(vtn + (size_t)gr * Lc + gc);
            vr[1] = *(const half8*)(vtn + (size_t)(gr + 32) * Lc + gc);
        }
        __syncthreads();   // single barrier per iteration (double-buffer makes it sufficient)

        const int  slo0  = q0 + 32 * wv;
        const bool live0 = (j * BN <= slo0 + 15);
        const bool live1 = (j * BN <= slo0 + 31);

        // ---- S^T = K * Q^T : D[key][qrow]; K-frags shared by both strips ----
        floatx4 sacc[2][4] = {};
        #pragma unroll
        for (int kb = 0; kb < 4; ++kb)
            #pragma unroll
            for (int kf = 0; kf < 2; ++kf) {
                bf16x8 ka = *(const bf16x8*)&Ks[(16 * kb + lm) * LDP + kf * 32 + quad * 8];
                if (live0) sacc[0][kb] = __builtin_amdgcn_mfma_f32_16x16x32_bf16(ka, qa[0][kf], sacc[0][kb], 0, 0, 0);
                if (live1) sacc[1][kb] = __builtin_amdgcn_mfma_f32_16x16x32_bf16(ka, qa[1][kf], sacc[1][kb], 0, 0, 0);
            }

        // ---- Taylor + causal mask + z, in registers; pack W as half8 B-frags per 32-key group ----
        half8 wf[2][2];
        const bool live[2] = {live0, live1};
        #pragma unroll
        for (int st = 0; st < 2; ++st) {
            if (!live[st]) continue;
            const int  strip_lo = slo0 + 16 * st;
            const bool nm   = (j * BN + 63 > strip_lo);
            const int  qrow = strip_lo + lm;
            #pragma unroll
            for (int kb = 0; kb < 4; ++kb) {
                #pragma unroll
                for (int r = 0; r < 4; ++r) {
                    const float a = __builtin_fmaf(sacc[st][kb][r], 0.125f, 1.0f); // s+1
                    float w = __builtin_fmaf(a, 0.5f * a, 0.5f);                   // 0.5(s+1)^2+0.5
                    if (nm) {
                        const int key = j * BN + 16 * kb + 4 * quad + r;
                        w = (key <= qrow) ? w : 0.0f;
                    }
                    zacc[st] += w;
                    wf[st][kb >> 1][(kb & 1) * 4 + r] = (_Float16)w;
                }
            }
        }

        // ---- O^T += V^T * W^T : A = permuted V^T b128 frags, B = wf (registers), K=32 ----
        #pragma unroll
        for (int db = 0; db < 4; ++db)
            #pragma unroll
            for (int grp = 0; grp < 2; ++grp) {
                half8 va = *(const half8*)&VT[(16 * db + lm) * LDP + 32 * grp + 8 * quad];
                if (live0) oacc[0][db] = __builtin_amdgcn_mfma_f32_16x16x32_f16(va, wf[0][grp], oacc[0][db], 0, 0, 0);
                if (live1) oacc[1][db] = __builtin_amdgcn_mfma_f32_16x16x32_f16(va, wf[1][grp], oacc[1][db], 0, 0, 0);
            }
    }

    // ---- finalize: z reduce across quads (lanes ^16, ^32), normalize, store ----
    #pragma unroll
    for (int st = 0; st < 2; ++st) {
        float z = zacc[st];
        z += __shfl_xor(z, 16);
        z += __shfl_xor(z, 32);
        const float inv = 1.0f / (z + 1e-6f);
        const int qrow = q0 + 32 * wv + 16 * st + lm;
        float* orow = op + ((size_t)bh * Lc + qrow) * Dc;
        #pragma unroll
        for (int db = 0; db < 4; ++db)
            #pragma unroll
            for (int r = 0; r < 4; ++r)
                orow[16 * db + 4 * quad + r] = oacc[st][db][r] * inv;
    }
}

extern "C" void kernel_launch(void* const* d_in, const int* in_sizes, int n_in,
                              void* d_out, int out_size, void* d_ws, size_t ws_size,
                              hipStream_t stream) {
    const float* q = (const float*)d_in[0];
    const float* k = (const float*)d_in[1];
    const float* v = (const float*)d_in[2];
    float* o = (float*)d_out;

    __bf16*   k16 = (__bf16*)d_ws;                                        // 8 MB
    _Float16* v16 = (_Float16*)((char*)d_ws + (size_t)BHn * Lc * Dc * 2); // 8 MB

    prep<<<dim3(2048), dim3(256), 0, stream>>>(k, v, k16, v16);
    taylor_attn<<<dim3(NQT * BHn), dim3(256), 0, stream>>>(q, k16, v16, o);
}